// Round 1
// baseline (849.697 us; speedup 1.0000x reference)
//
#include <hip/hip_runtime.h>

#define L_ 28
#define E_ 1024
#define H_ 8
#define D_ 128
#define B_ 2
#define S_ 1024

typedef __bf16 bf16x8 __attribute__((ext_vector_type(8)));
typedef float f32x4 __attribute__((ext_vector_type(4)));

// pack two fp32 -> two bf16 (RNE), low = a, high = b
__device__ __forceinline__ unsigned int f2bf2(float a, float b) {
  unsigned int ua = __builtin_bit_cast(unsigned int, a);
  ua += 0x7fffu + ((ua >> 16) & 1u);
  unsigned int ub = __builtin_bit_cast(unsigned int, b);
  ub += 0x7fffu + ((ub >> 16) & 1u);
  return (ua >> 16) | (ub & 0xffff0000u);
}

// direct global->LDS, 16B per lane. LDS dest is wave-uniform base + lane*16.
__device__ __forceinline__ void gll16(const void* g, void* l) {
  __builtin_amdgcn_global_load_lds(
      (const __attribute__((address_space(1))) unsigned int*)g,
      (__attribute__((address_space(3))) unsigned int*)l, 16, 0, 0);
}

// ============================================================================
// Workspace layout (bytes):
//   wsW  @ 0          : 28*2*8*16 tiles * 16384B = 117,440,512  bf16(W*lnw), swizzled
//   wsA  @ 117440512  : 16*16 tiles * 16384B     =   4,194,304  bf16(x), swizzled
//   wsSum@ 121634816  : 2048 * 4                 =       8,192  fp32 row sumsq of x
// Tile = 128 rows x 64 cols bf16 (16KB) stored as 1024 chunks of 16B.
// Swizzle (T2, m201): logical chunk (row, c) stored at position row*8 + (c ^ (row&7)).
// The main kernel's global_load_lds writes LDS linearly; ds_read applies the same XOR
// -> conflict-free b128 fragment reads (G4 / both-sides-or-neither rule m104/m231).
// ============================================================================
#define TILE_B 16384
#define WS_W_OFF   0ull
#define WS_A_OFF   117440512ull
#define WS_SUM_OFF 121634816ull
#define WS_NEED    121643008ull

// ---- prep 1: Wk/Wv fp32 -> bf16 with ln_w folded, tiled+swizzled -------------
// one thread per 16B output chunk; 7,340,032 chunks -> 28672 blocks x 256
__global__ __launch_bounds__(256) void prep_w_kernel(
    const float* __restrict__ Wk, const float* __restrict__ Wv,
    const float* __restrict__ lnw, unsigned short* __restrict__ wsW)
{
  const int idx = blockIdx.x * 256 + threadIdx.x;   // ws chunk position
  const int tile = idx >> 10;                       // [l][kv][nb][ks]
  const int p = idx & 1023;
  const int row = p >> 3;
  const int c = (p & 7) ^ (row & 7);                // logical chunk column
  const int ks = tile & 15;
  const int nb = (tile >> 4) & 7;
  const int kv = (tile >> 7) & 1;
  const int l  = tile >> 8;
  const float* src = (kv ? Wv : Wk) + (size_t)l * E_ * E_ +
                     (size_t)(nb * 128 + row) * E_ + ks * 64 + c * 8;
  const float* lw = lnw + l * E_ + ks * 64 + c * 8;
  const float4 w0 = *reinterpret_cast<const float4*>(src);
  const float4 w1 = *reinterpret_cast<const float4*>(src + 4);
  const float4 l0 = *reinterpret_cast<const float4*>(lw);
  const float4 l1 = *reinterpret_cast<const float4*>(lw + 4);
  uint4 o;
  o.x = f2bf2(w0.x * l0.x, w0.y * l0.y);
  o.y = f2bf2(w0.z * l0.z, w0.w * l0.w);
  o.z = f2bf2(w1.x * l1.x, w1.y * l1.y);
  o.w = f2bf2(w1.z * l1.z, w1.w * l1.w);
  *reinterpret_cast<uint4*>(reinterpret_cast<char*>(wsW) + (size_t)idx * 16) = o;
}

// ---- prep 2: x fp32 -> bf16 tiled+swizzled, plus per-row sumsq ---------------
// one wave per row; 2048 rows -> 512 blocks x 256 (4 waves)
__global__ __launch_bounds__(256) void prep_x_kernel(
    const float* __restrict__ x, unsigned short* __restrict__ wsA,
    float* __restrict__ wsSum)
{
  const int lane = threadIdx.x & 63;
  const int r = blockIdx.x * 4 + (threadIdx.x >> 6);
  const int mb = r >> 7, rt = r & 127;
  const float* src = x + (size_t)r * E_;
  float sq = 0.f;
  #pragma unroll
  for (int it = 0; it < 2; ++it) {
    const int j = it * 64 + lane;                   // chunk 0..127 of this row
    const int ksj = j >> 3, cj = j & 7;
    const float4 a0 = *reinterpret_cast<const float4*>(src + j * 8);
    const float4 a1 = *reinterpret_cast<const float4*>(src + j * 8 + 4);
    sq += a0.x * a0.x + a0.y * a0.y + a0.z * a0.z + a0.w * a0.w +
          a1.x * a1.x + a1.y * a1.y + a1.z * a1.z + a1.w * a1.w;
    uint4 o;
    o.x = f2bf2(a0.x, a0.y);
    o.y = f2bf2(a0.z, a0.w);
    o.z = f2bf2(a1.x, a1.y);
    o.w = f2bf2(a1.z, a1.w);
    const size_t pos = (size_t)(mb * 16 + ksj) * 1024 + rt * 8 + (cj ^ (rt & 7));
    *reinterpret_cast<uint4*>(reinterpret_cast<char*>(wsA) + pos * 16) = o;
  }
  #pragma unroll
  for (int off = 1; off < 64; off <<= 1) sq += __shfl_xor(sq, off, 64);
  if (lane == 0) wsSum[r] = sq;
}

// ---- main: pure bf16 GEMM (global_load_lds staged) + rho/k-rmsnorm/RoPE ------
// grid 3584 = 28 layers * 16 m-tiles * 8 heads; 256 thr = 4 waves, 32 rows each.
__global__ __launch_bounds__(256, 2) void fused_main_kernel(
    const unsigned short* __restrict__ wsA,
    const unsigned short* __restrict__ wsW,
    const float* __restrict__ wsSum,
    const float* __restrict__ scales,
    const float* __restrict__ knw,
    float* __restrict__ out)
{
  __shared__ unsigned short sA[8192];   // 16KB tile, linear (gll writes here)
  __shared__ unsigned short sK[8192];
  __shared__ unsigned short sV[8192];
  __shared__ float s_sumsq[128];
  __shared__ float s_knw[128];

  const int t = threadIdx.x;
  // XCD-bijective swizzle (3584 % 8 == 0): the 16 m-blocks sharing one W slice
  // land on one XCD's L2 instead of 8 (T1, m192/m204).
  const int logical = (blockIdx.x & 7) * 448 + (blockIdx.x >> 3);
  const int l = logical >> 7;
  const int n_idx = (logical >> 4) & 7;
  const int m_idx = logical & 15;

  if (t < 128) {
    s_sumsq[t] = wsSum[m_idx * 128 + t];
    s_knw[t] = knw[l * D_ + t];
  }

  const int lane = t & 63;
  const int wv = t >> 6;
  const int col16 = lane & 15;
  const int quad = lane >> 4;

  // staging source bases (pre-swizzled in ws, so source is linear per tile)
  const char* gA = reinterpret_cast<const char*>(wsA) + (size_t)(m_idx * 16) * TILE_B;
  const char* gK = reinterpret_cast<const char*>(wsW) + (size_t)((l * 2 + 0) * 8 + n_idx) * 16 * TILE_B;
  const char* gV = reinterpret_cast<const char*>(wsW) + (size_t)((l * 2 + 1) * 8 + n_idx) * 16 * TILE_B;
  const int lnoff = wv * 4096 + lane * 16;          // per-lane byte offset, j adds 1024

  // ds_read fragment offsets: logical (row, chunk c) lives at row*128 + (c^(row&7))*16.
  // rows used are wv*32+col16(+16) and nt*16+col16 -> row&7 == col16&7 always.
  const int slot0 = ((quad)     ^ (col16 & 7)) << 4;   // kk=0: c = quad
  const int slot1 = ((quad + 4) ^ (col16 & 7)) << 4;   // kk=1: c = 4+quad
  const int arow = (wv * 32 + col16) * 128;
  const int brow = col16 * 128;
  const char* pA = reinterpret_cast<const char*>(sA);
  const char* pK = reinterpret_cast<const char*>(sK);
  const char* pV = reinterpret_cast<const char*>(sV);

  f32x4 accK[2][8], accV[2][8];
  #pragma unroll
  for (int i = 0; i < 2; ++i)
    #pragma unroll
    for (int j = 0; j < 8; ++j) {
      accK[i][j] = (f32x4){0.f, 0.f, 0.f, 0.f};
      accV[i][j] = (f32x4){0.f, 0.f, 0.f, 0.f};
    }

  for (int ks = 0; ks < 16; ++ks) {
    __syncthreads();                                // prev iteration's LDS reads done
    const char* a = gA + (size_t)ks * TILE_B;
    const char* k = gK + (size_t)ks * TILE_B;
    const char* v = gV + (size_t)ks * TILE_B;
    #pragma unroll
    for (int j = 0; j < 4; ++j) {
      const int so = wv * 4096 + j * 1024;          // wave-uniform LDS dst
      gll16(a + lnoff + j * 1024, (char*)sA + so);
      gll16(k + lnoff + j * 1024, (char*)sK + so);
      gll16(v + lnoff + j * 1024, (char*)sV + so);
    }
    __syncthreads();                                // compiler drains vmcnt(0) here

    #pragma unroll
    for (int kk = 0; kk < 2; ++kk) {
      const int sl = kk ? slot1 : slot0;
      bf16x8 a0 = *reinterpret_cast<const bf16x8*>(pA + arow + sl);
      bf16x8 a1 = *reinterpret_cast<const bf16x8*>(pA + arow + 2048 + sl);
      #pragma unroll
      for (int nt = 0; nt < 8; ++nt) {
        bf16x8 bk = *reinterpret_cast<const bf16x8*>(pK + brow + nt * 2048 + sl);
        accK[0][nt] = __builtin_amdgcn_mfma_f32_16x16x32_bf16(a0, bk, accK[0][nt], 0, 0, 0);
        accK[1][nt] = __builtin_amdgcn_mfma_f32_16x16x32_bf16(a1, bk, accK[1][nt], 0, 0, 0);
        bf16x8 bv = *reinterpret_cast<const bf16x8*>(pV + brow + nt * 2048 + sl);
        accV[0][nt] = __builtin_amdgcn_mfma_f32_16x16x32_bf16(a0, bv, accV[0][nt], 0, 0, 0);
        accV[1][nt] = __builtin_amdgcn_mfma_f32_16x16x32_bf16(a1, bv, accV[1][nt], 0, 0, 0);
      }
    }
  }

  // ---- epilogue: rho, k-rmsnorm (16-lane shuffle), RoPE, store ----
  const int m_base = m_idx * 128;
  const float scale = scales[l];
  float freq[8], kw8[8];
  #pragma unroll
  for (int nt = 0; nt < 8; ++nt) {
    const int d = nt * 16 + col16;
    freq[nt] = exp2f(-(float)(d & 63) * 0.31143075889569023f);
    kw8[nt] = s_knw[d];
  }
  const size_t VOFF = (size_t)L_ * B_ * H_ * S_ * D_;

  #pragma unroll
  for (int mt = 0; mt < 2; ++mt) {
    #pragma unroll
    for (int reg = 0; reg < 4; ++reg) {
      const int rl = wv * 32 + mt * 16 + quad * 4 + reg;
      const int mg = m_base + rl;
      const int bb = mg >> 10;
      const int ss = mg & 1023;
      const float ms = s_sumsq[rl] * (1.0f / 1024.0f);
      const float rho = scale * rsqrtf(scale * scale * ms + 1e-6f);
      float kvv[8], vvv[8];
      float ksum = 0.f;
      #pragma unroll
      for (int nt = 0; nt < 8; ++nt) {
        kvv[nt] = rho * accK[mt][nt][reg];
        vvv[nt] = rho * accV[mt][nt][reg];
        ksum += kvv[nt] * kvv[nt];
      }
      #pragma unroll
      for (int off = 1; off < 16; off <<= 1) ksum += __shfl_xor(ksum, off, 64);
      const float r2 = rsqrtf(ksum * (1.0f / 128.0f) + 1e-6f);
      float kn[8];
      #pragma unroll
      for (int nt = 0; nt < 8; ++nt) kn[nt] = kvv[nt] * r2 * kw8[nt];
      const float sf = (float)ss;
      const size_t base = ((((size_t)(l * B_ + bb)) * H_ + n_idx) * S_ + ss) * D_;
      #pragma unroll
      for (int nt = 0; nt < 8; ++nt) {
        const float ang = sf * freq[nt];
        const float cs = __cosf(ang);
        const float sn = __sinf(ang);
        const float rot = (nt < 4) ? -kn[nt + 4] : kn[nt - 4];
        out[base + nt * 16 + col16] = kn[nt] * cs + rot * sn;
        out[VOFF + base + nt * 16 + col16] = vvv[nt];
      }
    }
  }
}

// ============================================================================
// legacy fallback (harness-verified @1899.5us) — used only if ws_size < WS_NEED
// ============================================================================
__global__ __launch_bounds__(256, 2) void fused_kv_kernel(
    const float* __restrict__ x, const float* __restrict__ scales,
    const float* __restrict__ lnw, const float* __restrict__ Wk,
    const float* __restrict__ Wv, const float* __restrict__ knw,
    float* __restrict__ out)
{
  __shared__ unsigned short sA[128][72];
  __shared__ unsigned short sK[128][72];
  __shared__ unsigned short sV[128][72];
  __shared__ float s_lnw[E_];
  __shared__ float s_knw[D_];
  __shared__ float s_sumsq[128];

  const int t = threadIdx.x;
  const int bx = blockIdx.x;
  const int l = bx >> 7;
  const int n_idx = (bx >> 4) & 7;
  const int m_idx = bx & 15;
  const int m_base = m_idx * 128;
  const int n_base = n_idx * 128;

  *reinterpret_cast<float4*>(&s_lnw[t * 4]) =
      *reinterpret_cast<const float4*>(&lnw[(size_t)l * E_ + t * 4]);
  if (t < D_) s_knw[t] = knw[l * D_ + t];

  const int c4 = t & 15;
  const int r0 = t >> 4;

  const float* xg  = x  + (size_t)(m_base + r0) * E_ + c4 * 4;
  const float* wkg = Wk + (size_t)l * E_ * E_ + (size_t)(n_base + r0) * E_ + c4 * 4;
  const float* wvg = Wv + (size_t)l * E_ * E_ + (size_t)(n_base + r0) * E_ + c4 * 4;

  const int lane = t & 63;
  const int wv = t >> 6;
  const int col16 = lane & 15;
  const int quad = lane >> 4;

  f32x4 accK[2][8], accV[2][8];
  #pragma unroll
  for (int i = 0; i < 2; ++i)
    #pragma unroll
    for (int j = 0; j < 8; ++j) {
      accK[i][j] = (f32x4){0.f, 0.f, 0.f, 0.f};
      accV[i][j] = (f32x4){0.f, 0.f, 0.f, 0.f};
    }
  float sq[8] = {0.f, 0.f, 0.f, 0.f, 0.f, 0.f, 0.f, 0.f};

  for (int ks = 0; ks < 16; ++ks) {
    const int k0 = ks * 64;
    float4 av[8];
    #pragma unroll
    for (int p = 0; p < 8; ++p)
      av[p] = *reinterpret_cast<const float4*>(xg + (size_t)(p * 16) * E_ + k0);

    __syncthreads();

    #pragma unroll
    for (int p = 0; p < 8; ++p) {
      sq[p] += av[p].x * av[p].x + av[p].y * av[p].y +
               av[p].z * av[p].z + av[p].w * av[p].w;
      uint2 pk;
      pk.x = f2bf2(av[p].x, av[p].y);
      pk.y = f2bf2(av[p].z, av[p].w);
      *reinterpret_cast<uint2*>(&sA[r0 + p * 16][c4 * 4]) = pk;
    }
    const float4 lw = *reinterpret_cast<const float4*>(&s_lnw[k0 + c4 * 4]);
    #pragma unroll
    for (int p = 0; p < 8; ++p) {
      float4 w4 = *reinterpret_cast<const float4*>(wkg + (size_t)(p * 16) * E_ + k0);
      uint2 pk;
      pk.x = f2bf2(w4.x * lw.x, w4.y * lw.y);
      pk.y = f2bf2(w4.z * lw.z, w4.w * lw.w);
      *reinterpret_cast<uint2*>(&sK[r0 + p * 16][c4 * 4]) = pk;
    }
    #pragma unroll
    for (int p = 0; p < 8; ++p) {
      float4 w4 = *reinterpret_cast<const float4*>(wvg + (size_t)(p * 16) * E_ + k0);
      uint2 pk;
      pk.x = f2bf2(w4.x * lw.x, w4.y * lw.y);
      pk.y = f2bf2(w4.z * lw.z, w4.w * lw.w);
      *reinterpret_cast<uint2*>(&sV[r0 + p * 16][c4 * 4]) = pk;
    }
    __syncthreads();

    #pragma unroll
    for (int kk = 0; kk < 2; ++kk) {
      const int ko = kk * 32 + quad * 8;
      bf16x8 a0 = *reinterpret_cast<const bf16x8*>(&sA[wv * 32 + col16][ko]);
      bf16x8 a1 = *reinterpret_cast<const bf16x8*>(&sA[wv * 32 + 16 + col16][ko]);
      #pragma unroll
      for (int nt = 0; nt < 8; ++nt) {
        bf16x8 bk = *reinterpret_cast<const bf16x8*>(&sK[nt * 16 + col16][ko]);
        accK[0][nt] = __builtin_amdgcn_mfma_f32_16x16x32_bf16(a0, bk, accK[0][nt], 0, 0, 0);
        accK[1][nt] = __builtin_amdgcn_mfma_f32_16x16x32_bf16(a1, bk, accK[1][nt], 0, 0, 0);
        bf16x8 bv = *reinterpret_cast<const bf16x8*>(&sV[nt * 16 + col16][ko]);
        accV[0][nt] = __builtin_amdgcn_mfma_f32_16x16x32_bf16(a0, bv, accV[0][nt], 0, 0, 0);
        accV[1][nt] = __builtin_amdgcn_mfma_f32_16x16x32_bf16(a1, bv, accV[1][nt], 0, 0, 0);
      }
    }
  }

  __syncthreads();
  float* red = reinterpret_cast<float*>(&sA[0][0]);
  #pragma unroll
  for (int p = 0; p < 8; ++p) red[(r0 + p * 16) * 16 + c4] = sq[p];
  __syncthreads();
  if (t < 128) {
    float s = 0.f;
    #pragma unroll
    for (int i = 0; i < 16; ++i) s += red[t * 16 + i];
    s_sumsq[t] = s;
  }
  __syncthreads();

  const float scale = scales[l];
  float freq[8], kw8[8];
  #pragma unroll
  for (int nt = 0; nt < 8; ++nt) {
    const int d = nt * 16 + col16;
    freq[nt] = exp2f(-(float)(d & 63) * 0.31143075889569023f);
    kw8[nt] = s_knw[d];
  }
  const size_t VOFF = (size_t)L_ * B_ * H_ * S_ * D_;

  #pragma unroll
  for (int mt = 0; mt < 2; ++mt) {
    #pragma unroll
    for (int reg = 0; reg < 4; ++reg) {
      const int rl = wv * 32 + mt * 16 + quad * 4 + reg;
      const int mg = m_base + rl;
      const int bb = mg >> 10;
      const int ss = mg & 1023;
      const float ms = s_sumsq[rl] * (1.0f / 1024.0f);
      const float rho = scale * rsqrtf(scale * scale * ms + 1e-6f);
      float kvv[8], vvv[8];
      float ksum = 0.f;
      #pragma unroll
      for (int nt = 0; nt < 8; ++nt) {
        kvv[nt] = rho * accK[mt][nt][reg];
        vvv[nt] = rho * accV[mt][nt][reg];
        ksum += kvv[nt] * kvv[nt];
      }
      #pragma unroll
      for (int off = 1; off < 16; off <<= 1) ksum += __shfl_xor(ksum, off, 64);
      const float r2 = rsqrtf(ksum * (1.0f / 128.0f) + 1e-6f);
      float kn[8];
      #pragma unroll
      for (int nt = 0; nt < 8; ++nt) kn[nt] = kvv[nt] * r2 * kw8[nt];
      const float sf = (float)ss;
      const size_t base = ((((size_t)(l * B_ + bb)) * H_ + n_idx) * S_ + ss) * D_;
      #pragma unroll
      for (int nt = 0; nt < 8; ++nt) {
        const float ang = sf * freq[nt];
        const float cs = __cosf(ang);
        const float sn = __sinf(ang);
        const float rot = (nt < 4) ? -kn[nt + 4] : kn[nt - 4];
        out[base + nt * 16 + col16] = kn[nt] * cs + rot * sn;
        out[VOFF + base + nt * 16 + col16] = vvv[nt];
      }
    }
  }
}

extern "C" void kernel_launch(void* const* d_in, const int* in_sizes, int n_in,
                              void* d_out, int out_size, void* d_ws, size_t ws_size,
                              hipStream_t stream) {
  const float* x      = (const float*)d_in[0];
  const float* scales = (const float*)d_in[1];
  const float* lnw    = (const float*)d_in[2];
  const float* Wk     = (const float*)d_in[3];
  const float* Wv     = (const float*)d_in[4];
  const float* knw    = (const float*)d_in[5];
  float* out = (float*)d_out;

  if (d_ws != nullptr && ws_size >= WS_NEED) {
    unsigned short* wsW = (unsigned short*)((char*)d_ws + WS_W_OFF);
    unsigned short* wsA = (unsigned short*)((char*)d_ws + WS_A_OFF);
    float* wsSum        = (float*)((char*)d_ws + WS_SUM_OFF);
    prep_w_kernel<<<dim3(28672), 256, 0, stream>>>(Wk, Wv, lnw, wsW);
    prep_x_kernel<<<dim3(512), 256, 0, stream>>>(x, wsA, wsSum);
    fused_main_kernel<<<dim3(L_ * 16 * 8), 256, 0, stream>>>(wsA, wsW, wsSum, scales, knw, out);
  } else {
    fused_kv_kernel<<<dim3(L_ * 16 * 8), 256, 0, stream>>>(x, scales, lnw, Wk, Wv, knw, out);
  }
}